// Round 3
// baseline (362.417 us; speedup 1.0000x reference)
//
#include <hip/hip_runtime.h>

#define D_DIM 1024
#define NROW  8192
#define ROWB  2048      // bytes per bf16 row

typedef short bf16x8 __attribute__((ext_vector_type(8)));
typedef float f32x4  __attribute__((ext_vector_type(4)));

typedef const __attribute__((address_space(1))) void g_void;
typedef __attribute__((address_space(3))) void lds_void;

__device__ __forceinline__ void gload16(const void* g, void* l) {
    __builtin_amdgcn_global_load_lds((g_void*)g, (lds_void*)l, 16, 0, 0);
}

__device__ __forceinline__ unsigned short f2bf(float f) {
    unsigned int b = __float_as_uint(f);
    unsigned int r = (b + 0x7FFFu + ((b >> 16) & 1u)) >> 16;
    return (unsigned short)r;
}

// One block per row: fp32 -> bf16 conversion + fp32 row sum-of-squares.
__global__ __launch_bounds__(256) void mk_conv(const float* __restrict__ src,
                                               unsigned short* __restrict__ dst,
                                               float* __restrict__ rowsq,
                                               float* out, int zero_out) {
    const int row = blockIdx.x;
    const int tid = threadIdx.x;
    const float4* s4 = (const float4*)(src + (size_t)row * D_DIM);
    float4 v = s4[tid];
    ushort4 o;
    o.x = f2bf(v.x); o.y = f2bf(v.y); o.z = f2bf(v.z); o.w = f2bf(v.w);
    ((ushort4*)(dst + (size_t)row * D_DIM))[tid] = o;
    float ss = v.x * v.x + v.y * v.y + v.z * v.z + v.w * v.w;
#pragma unroll
    for (int off = 32; off; off >>= 1) ss += __shfl_down(ss, off);
    __shared__ float red[4];
    if ((tid & 63) == 0) red[tid >> 6] = ss;
    __syncthreads();
    if (tid == 0) rowsq[row] = red[0] + red[1] + red[2] + red[3];
    if (zero_out && row == 0 && tid == 0) out[0] = 0.0f;
}

// 256x256-tile fused MK-MMD GEMM. 8 waves (2Mx4N), 16x16x32 bf16 MFMA.
// Ring of 4 K-half slots (BK=32); ONE barrier + ONE counted vmcnt per K-half:
//   [vmcnt(8) -> barrier -> STAGE(kh+3) + 12 ds_reads -> lgkm(0) -> 32 MFMA]
// Long inter-barrier window lets waves drift -> LDS reads overlap MFMA.
// Symmetric matrices (SS/TT) computed upper-triangular with weight 2.
__global__ __launch_bounds__(512) void mk_gemm(const unsigned short* __restrict__ Sb,
                                               const unsigned short* __restrict__ Tb,
                                               const float* __restrict__ s2,
                                               const float* __restrict__ t2,
                                               float* __restrict__ out) {
    // LDS: A slots [0,64K): slot*16384 ; B slots [64K,128K): 65536+slot*16384
    __shared__ __align__(16) char smem[131072];
    __shared__ float red[8];

    // bijective XCD swizzle (2080 = 8 * 260): each XCD gets a contiguous chunk
    const int bid = (blockIdx.x & 7) * 260 + (blockIdx.x >> 3);
    int m, ti, tj;
    if (bid < 1056) {                      // SS (528) then TT (528), ti<=tj
        m = (bid < 528) ? 0 : 2;
        int s = (bid < 528) ? bid : bid - 528;
        int t = 0;
        while (s >= 32 - t) { s -= 32 - t; ++t; }
        ti = t; tj = t + s;
    } else {                               // ST: full 32x32
        m = 1; int s = bid - 1056; ti = s >> 5; tj = s & 31;
    }

    const unsigned short* Abf = (m == 2) ? Tb : Sb;
    const unsigned short* Bbf = (m == 0) ? Sb : Tb;
    const float* x2a = (m == 2) ? t2 : s2;
    const float* x2b = (m == 0) ? s2 : t2;

    const int rowA0 = ti * 256, colB0 = tj * 256;

    const int tid = threadIdx.x;
    const int w = tid >> 6, lane = tid & 63;
    const int wr = w >> 2, wc = w & 3;     // wave grid 2M x 4N

    // ---- staging addressing (pre-swizzled global source, linear LDS dest) ----
    // LDS byte l (in 16KB slot): row = 2*(l>>7) + ((l>>6)&1), sb=(l>>4)&3
    // content[row][sb] = global[row][ kh*32 + (sb ^ ((row>>1)&3))*8 .. ]
    const int rowc  = 2 * (w * 8 + (lane >> 3)) + ((lane >> 2) & 1);
    const int ssb   = ((lane & 3) ^ ((lane >> 3) & 3)) << 4;
    const char* aS0 = (const char*)Abf + (size_t)(rowA0 + rowc) * ROWB + ssb;
    const char* bS0 = (const char*)Bbf + (size_t)(colB0 + rowc) * ROWB + ssb;
    char* ldsA = smem + w * 1024;          // + slot*16384 (+8192 for 2nd instr)
    char* ldsB = smem + 65536 + w * 1024;

    // ---- fragment read addressing (swizzled ds_read_b128) ----
    const int frow = lane & 15, fgrp = lane >> 4;
    const int rb   = (frow >> 1);
    const int xsb  = (fgrp ^ (rb & 3)) << 4;
    const int aRB  = (wr * 64 + rb) * 128 + (frow & 1) * 64 + xsb;
    const int bRB  = 65536 + (wc * 32 + rb) * 128 + (frow & 1) * 64 + xsb;

    f32x4 acc[8][4] = {};

#define STAGE_A(khv, slot) do {                                            \
    const size_t ko_ = (size_t)(khv) * 64;                                 \
    gload16(aS0 + ko_,          ldsA + (slot) * 16384);                    \
    gload16(aS0 + ko_ + 262144, ldsA + (slot) * 16384 + 8192);             \
} while (0)
#define STAGE_B(khv, slot) do {                                            \
    const size_t ko_ = (size_t)(khv) * 64;                                 \
    gload16(bS0 + ko_,          ldsB + (slot) * 16384);                    \
    gload16(bS0 + ko_ + 262144, ldsB + (slot) * 16384 + 8192);             \
} while (0)

    // prologue: stage K-halves 0,1,2 into slots 0,1,2 (12 gloads in flight)
    STAGE_A(0, 0); STAGE_B(0, 0);
    STAGE_A(1, 1); STAGE_B(1, 1);
    STAGE_A(2, 2); STAGE_B(2, 2);

    for (int g = 0; g < 8; ++g) {
#pragma unroll
        for (int j = 0; j < 4; ++j) {                  // kh = 4g+j, slot = j
            const int sA = j * 16384;
            // publish landing of kh (own gloads; barrier publishes all waves)
            if (j == 2 && g == 7)      asm volatile("s_waitcnt vmcnt(4)" ::: "memory");
            else if (j == 3 && g == 7) asm volatile("s_waitcnt vmcnt(0)" ::: "memory");
            else                       asm volatile("s_waitcnt vmcnt(8)" ::: "memory");
            __builtin_amdgcn_s_barrier();
            __builtin_amdgcn_sched_barrier(0);
            // stage kh+3 into slot (j+3)&3 (WAR-safe: past the barrier)
            if (j == 0 || g < 7) {
                const int kh3 = 4 * g + j + 3, sT = (j + 3) & 3;
                STAGE_A(kh3, sT); STAGE_B(kh3, sT);
            }
            bf16x8 av[8], bv[4];
#pragma unroll
            for (int mi = 0; mi < 8; ++mi)
                av[mi] = *(const bf16x8*)(smem + sA + aRB + mi * 1024);
#pragma unroll
            for (int ni = 0; ni < 4; ++ni)
                bv[ni] = *(const bf16x8*)(smem + sA + bRB + ni * 1024);
            asm volatile("s_waitcnt lgkmcnt(0)" ::: "memory");
            __builtin_amdgcn_sched_barrier(0);
            __builtin_amdgcn_s_setprio(1);
#pragma unroll
            for (int ni = 0; ni < 4; ++ni)
#pragma unroll
                for (int mi = 0; mi < 8; ++mi)
                    acc[mi][ni] = __builtin_amdgcn_mfma_f32_16x16x32_bf16(
                        av[mi], bv[ni], acc[mi][ni], 0, 0, 0);
            __builtin_amdgcn_s_setprio(0);
            __builtin_amdgcn_sched_barrier(0);
        }
    }

    // ---- fused epilogue: d2 -> sum over 6 bandwidths of exp(-d2/bw) ----
    // C/D layout: col = lane&15 (B row), row = (lane>>4)*4 + reg (A row)
    float lsum = 0.0f;
    const int grb = rowA0 + wr * 128 + fgrp * 4;
    const int gcb = colB0 + wc * 64 + frow;
    float y2v[4];
#pragma unroll
    for (int ni = 0; ni < 4; ++ni) y2v[ni] = x2b[gcb + ni * 16];
#pragma unroll
    for (int mi = 0; mi < 8; ++mi) {
#pragma unroll
        for (int r = 0; r < 4; ++r) {
            const int gr = grb + mi * 16 + r;
            const float xa = x2a[gr];
#pragma unroll
            for (int ni = 0; ni < 4; ++ni) {
                float d2 = fmaxf(xa + y2v[ni] - 2.0f * acc[mi][ni][r], 0.0f);
                // t = exp(-d2/100); bw {100,50,20,10,5,1} -> t^{1,2,5,10,20,100}
                float t1   = __expf(d2 * -0.01f);
                float t2v  = t1 * t1;
                float t4   = t2v * t2v;
                float t5   = t4 * t1;
                float t10  = t5 * t5;
                float t20  = t10 * t10;
                float t40  = t20 * t20;
                float t80  = t40 * t40;
                float t100 = t80 * t20;
                float ksum = t1 + t2v + t5 + t10 + t20 + t100;
                if (m != 1 && gr == gcb + ni * 16) ksum = 6.0f;  // exact diagonal
                lsum += ksum;
            }
        }
    }

#pragma unroll
    for (int off = 32; off; off >>= 1) lsum += __shfl_down(lsum, off);
    __syncthreads();
    if (lane == 0) red[w] = lsum;
    __syncthreads();
    if (tid == 0) {
        float wgt = (m == 1) ? -2.0f : ((ti == tj) ? 1.0f : 2.0f);
        float tot = 0.0f;
#pragma unroll
        for (int i = 0; i < 8; ++i) tot += red[i];
        // loss = (S_ss - 2*S_st + S_tt) / (6 * 8192 * 8192)
        atomicAdd(out, tot * (wgt / 402653184.0f));
    }
}

extern "C" void kernel_launch(void* const* d_in, const int* in_sizes, int n_in,
                              void* d_out, int out_size, void* d_ws, size_t ws_size,
                              hipStream_t stream) {
    const float* src = (const float*)d_in[0];
    const float* tgt = (const float*)d_in[1];
    float* out = (float*)d_out;

    unsigned short* Sb = (unsigned short*)d_ws;
    unsigned short* Tb = Sb + (size_t)NROW * D_DIM;
    float* s2 = (float*)(Tb + (size_t)NROW * D_DIM);
    float* t2 = s2 + NROW;

    mk_conv<<<NROW, 256, 0, stream>>>(src, Sb, s2, out, 1);
    mk_conv<<<NROW, 256, 0, stream>>>(tgt, Tb, t2, out, 0);
    mk_gemm<<<2080, 512, 0, stream>>>(Sb, Tb, s2, t2, out);
}

// Round 4
// 357.282 us; speedup vs baseline: 1.0144x; 1.0144x over previous
//
#include <hip/hip_runtime.h>

#define D_DIM 1024
#define NROW  8192
#define ROWB  2048      // bytes per bf16 row
#define NTILE 2080      // 528 SS (tri) + 528 TT (tri) + 1024 ST
#define NKT   16        // K-tiles of 64 (K=1024)

typedef short bf16x8 __attribute__((ext_vector_type(8)));
typedef float f32x4  __attribute__((ext_vector_type(4)));

typedef const __attribute__((address_space(1))) void g_void;
typedef __attribute__((address_space(3))) void lds_void;

__device__ __forceinline__ void gload16(const void* g, void* l) {
    __builtin_amdgcn_global_load_lds((g_void*)g, (lds_void*)l, 16, 0, 0);
}

__device__ __forceinline__ unsigned short f2bf(float f) {
    unsigned int b = __float_as_uint(f);
    unsigned int r = (b + 0x7FFFu + ((b >> 16) & 1u)) >> 16;
    return (unsigned short)r;
}

// One block per row: fp32 -> bf16 conversion + fp32 row sum-of-squares.
__global__ __launch_bounds__(256) void mk_conv(const float* __restrict__ src,
                                               unsigned short* __restrict__ dst,
                                               float* __restrict__ rowsq,
                                               float* out, int* cnt, int zero_out) {
    const int row = blockIdx.x;
    const int tid = threadIdx.x;
    const float4* s4 = (const float4*)(src + (size_t)row * D_DIM);
    float4 v = s4[tid];
    ushort4 o;
    o.x = f2bf(v.x); o.y = f2bf(v.y); o.z = f2bf(v.z); o.w = f2bf(v.w);
    ((ushort4*)(dst + (size_t)row * D_DIM))[tid] = o;
    float ss = v.x * v.x + v.y * v.y + v.z * v.z + v.w * v.w;
#pragma unroll
    for (int off = 32; off; off >>= 1) ss += __shfl_down(ss, off);
    __shared__ float red[4];
    if ((tid & 63) == 0) red[tid >> 6] = ss;
    __syncthreads();
    if (tid == 0) rowsq[row] = red[0] + red[1] + red[2] + red[3];
    if (zero_out && row == 0 && tid == 0) { out[0] = 0.0f; *cnt = 0; }
}

// 256x256-tile fused MK-MMD GEMM, m201-faithful 8-phase schedule.
// BK=64, 2 dbuf (128KB LDS), 8 waves (2Mx4N), 16x16x32 bf16 MFMA.
// Per K-tile: 4 phases (Q00,Q01,Q11,Q10), reads 12/4/8/4 issued PRE-barrier,
// lgkmcnt(0) POST-barrier, 16 MFMA per phase, 1 staged half-tile per phase,
// one counted vmcnt(2) per K-tile. Persistent blocks + atomic ticket.
__global__ __launch_bounds__(512) void mk_gemm(const unsigned short* __restrict__ Sb,
                                               const unsigned short* __restrict__ Tb,
                                               const float* __restrict__ s2,
                                               const float* __restrict__ t2,
                                               float* __restrict__ out,
                                               int* __restrict__ cnt) {
    // LDS per buf (64KB): A-h0 +0, A-h1 +16K, B-h0 +32K, B-h1 +48K. 2 bufs.
    __shared__ __align__(16) char smem[131072];
    __shared__ float red[8];
    __shared__ int tks;

    const int tid = threadIdx.x;
    const int w = tid >> 6, lane = tid & 63;
    const int wr = w >> 2, wc = w & 3;       // wave grid 2M x 4N
    const int frow = lane & 15, fgrp = lane >> 4;

    // swizzled fragment-read granule offsets: g = ks*4+fgrp, pos = g ^ (row&7)
    const int gx0 = ((fgrp ^ (frow & 7)) << 4);
    const int gx1 = (((4 | fgrp) ^ (frow & 7)) << 4);

    // staging per-lane constants: row-in-chunk, pre-swizzled source granule
    const int srow = lane >> 3;                    // 0..7
    const int scol = ((lane & 7) ^ srow) << 4;     // global granule = pos ^ row&7

    for (;;) {
        if (tid == 0) tks = atomicAdd(cnt, 1);
        __syncthreads();
        const int t = tks;
        if (t >= NTILE) return;

        int m, ti, tj;
        if (t < 1056) {                      // SS (528) then TT (528), ti<=tj
            m = (t < 528) ? 0 : 2;
            int s = (t < 528) ? t : t - 528;
            int r = 0;
            while (s >= 32 - r) { s -= 32 - r; ++r; }
            ti = r; tj = r + s;
        } else {                             // ST: full 32x32
            m = 1; int s = t - 1056; ti = s >> 5; tj = s & 31;
        }

        const char* Abf = (const char*)((m == 2) ? Tb : Sb) + (size_t)(ti * 256) * ROWB;
        const char* Bbf = (const char*)((m == 0) ? Sb : Tb) + (size_t)(tj * 256) * ROWB;
        const float* x2a = (m == 2) ? t2 : s2;
        const float* x2b = (m == 0) ? s2 : t2;

        // per-lane staging source bases (half h adds h*128 rows = 262144 B)
        const char* aSrc = Abf + (size_t)(w * 16 + srow) * ROWB + scol;
        const char* bSrc = Bbf + (size_t)(w * 16 + srow) * ROWB + scol;

#define STAGE_AH(h, uu) do {                                                   \
    const char* s_ = aSrc + (h) * 262144 + (size_t)(uu) * 128;                 \
    char* d_ = smem + ((uu) & 1) * 65536 + (h) * 16384 + w * 2048;             \
    gload16(s_, d_); gload16(s_ + 16384, d_ + 1024);                           \
} while (0)
#define STAGE_BH(h, uu) do {                                                   \
    const char* s_ = bSrc + (h) * 262144 + (size_t)(uu) * 128;                 \
    char* d_ = smem + ((uu) & 1) * 65536 + 32768 + (h) * 16384 + w * 2048;     \
    gload16(s_, d_); gload16(s_ + 16384, d_ + 1024);                           \
} while (0)

        // prologue: tile0's 4 halves + A-h0(1); vmcnt(2) leaves A-h0(1) flying
        STAGE_AH(0, 0); STAGE_AH(1, 0); STAGE_BH(1, 0); STAGE_BH(0, 0);
        STAGE_AH(0, 1);
        asm volatile("s_waitcnt vmcnt(2)" ::: "memory");
        __builtin_amdgcn_s_barrier();

        f32x4 acc[8][4] = {};

        // wave fragment-read row offsets
        const int brow = (wc & 1) * 64;

#pragma unroll 2
        for (int u = 0; u < NKT; ++u) {
            const int bufc = (u & 1) * 65536;
            const char* Ah = smem + bufc + wr * 16384;
            const char* Bh = smem + bufc + 32768 + (wc >> 1) * 16384;
            bf16x8 av[4][2], bvlo[2][2], bvhi[2][2];

            // ========== P1 (Q00): av mi0-3, bvlo; stage A-h1(u+1), B-h1(u+1)
#pragma unroll
            for (int mi = 0; mi < 4; ++mi) {
                av[mi][0] = *(const bf16x8*)(Ah + (mi * 16 + frow) * 128 + gx0);
                av[mi][1] = *(const bf16x8*)(Ah + (mi * 16 + frow) * 128 + gx1);
            }
#pragma unroll
            for (int ni = 0; ni < 2; ++ni) {
                bvlo[ni][0] = *(const bf16x8*)(Bh + (brow + ni * 16 + frow) * 128 + gx0);
                bvlo[ni][1] = *(const bf16x8*)(Bh + (brow + ni * 16 + frow) * 128 + gx1);
            }
            if (u + 1 < NKT) { STAGE_AH(1, u + 1); STAGE_BH(1, u + 1); }
            asm volatile("s_waitcnt lgkmcnt(8)" ::: "memory");
            __builtin_amdgcn_sched_barrier(0);
            __builtin_amdgcn_s_barrier();
            asm volatile("s_waitcnt lgkmcnt(0)" ::: "memory");
            __builtin_amdgcn_sched_barrier(0);
            __builtin_amdgcn_s_setprio(1);
#pragma unroll
            for (int ni = 0; ni < 2; ++ni)
#pragma unroll
                for (int mi = 0; mi < 4; ++mi)
#pragma unroll
                    for (int ks = 0; ks < 2; ++ks)
                        acc[mi][ni] = __builtin_amdgcn_mfma_f32_16x16x32_bf16(
                            av[mi][ks], bvlo[ni][ks], acc[mi][ni], 0, 0, 0);
            __builtin_amdgcn_s_setprio(0);
            __builtin_amdgcn_sched_barrier(0);
            __builtin_amdgcn_s_barrier();

            // ========== P2 (Q01): bvhi; stage B-h0(u+1)
#pragma unroll
            for (int ni = 0; ni < 2; ++ni) {
                bvhi[ni][0] = *(const bf16x8*)(Bh + (brow + (2 + ni) * 16 + frow) * 128 + gx0);
                bvhi[ni][1] = *(const bf16x8*)(Bh + (brow + (2 + ni) * 16 + frow) * 128 + gx1);
            }
            if (u + 1 < NKT) STAGE_BH(0, u + 1);
            __builtin_amdgcn_sched_barrier(0);
            __builtin_amdgcn_s_barrier();
            asm volatile("s_waitcnt lgkmcnt(0)" ::: "memory");
            __builtin_amdgcn_sched_barrier(0);
            __builtin_amdgcn_s_setprio(1);
#pragma unroll
            for (int ni = 0; ni < 2; ++ni)
#pragma unroll
                for (int mi = 0; mi < 4; ++mi)
#pragma unroll
                    for (int ks = 0; ks < 2; ++ks)
                        acc[mi][2 + ni] = __builtin_amdgcn_mfma_f32_16x16x32_bf16(
                            av[mi][ks], bvhi[ni][ks], acc[mi][2 + ni], 0, 0, 0);
            __builtin_amdgcn_s_setprio(0);
            __builtin_amdgcn_sched_barrier(0);
            __builtin_amdgcn_s_barrier();

            // ========== P3 (Q11): av mi4-7 (overwrite); no stage
#pragma unroll
            for (int mi = 0; mi < 4; ++mi) {
                av[mi][0] = *(const bf16x8*)(Ah + (64 + mi * 16 + frow) * 128 + gx0);
                av[mi][1] = *(const bf16x8*)(Ah + (64 + mi * 16 + frow) * 128 + gx1);
            }
            __builtin_amdgcn_sched_barrier(0);
            __builtin_amdgcn_s_barrier();
            asm volatile("s_waitcnt lgkmcnt(0)" ::: "memory");
            __builtin_amdgcn_sched_barrier(0);
            __builtin_amdgcn_s_setprio(1);
#pragma unroll
            for (int ni = 0; ni < 2; ++ni)
#pragma unroll
                for (int mi = 0; mi < 4; ++mi)
#pragma unroll
                    for (int ks = 0; ks < 2; ++ks)
                        acc[4 + mi][2 + ni] = __builtin_amdgcn_mfma_f32_16x16x32_bf16(
                            av[mi][ks], bvhi[ni][ks], acc[4 + mi][2 + ni], 0, 0, 0);
            __builtin_amdgcn_s_setprio(0);
            __builtin_amdgcn_sched_barrier(0);
            __builtin_amdgcn_s_barrier();

            // ========== P4 (Q10): bvlo re-read; stage A-h0(u+2); vmcnt publish
#pragma unroll
            for (int ni = 0; ni < 2; ++ni) {
                bvlo[ni][0] = *(const bf16x8*)(Bh + (brow + ni * 16 + frow) * 128 + gx0);
                bvlo[ni][1] = *(const bf16x8*)(Bh + (brow + ni * 16 + frow) * 128 + gx1);
            }
            if (u + 2 < NKT) STAGE_AH(0, u + 2);
            if (u < NKT - 2)      asm volatile("s_waitcnt vmcnt(2)" ::: "memory");
            else if (u == NKT - 2) asm volatile("s_waitcnt vmcnt(0)" ::: "memory");
            __builtin_amdgcn_sched_barrier(0);
            __builtin_amdgcn_s_barrier();
            asm volatile("s_waitcnt lgkmcnt(0)" ::: "memory");
            __builtin_amdgcn_sched_barrier(0);
            __builtin_amdgcn_s_setprio(1);
#pragma unroll
            for (int ni = 0; ni < 2; ++ni)
#pragma unroll
                for (int mi = 0; mi < 4; ++mi)
#pragma unroll
                    for (int ks = 0; ks < 2; ++ks)
                        acc[4 + mi][ni] = __builtin_amdgcn_mfma_f32_16x16x32_bf16(
                            av[mi][ks], bvlo[ni][ks], acc[4 + mi][ni], 0, 0, 0);
            __builtin_amdgcn_s_setprio(0);
            __builtin_amdgcn_sched_barrier(0);
            __builtin_amdgcn_s_barrier();
        }

        // ---- fused epilogue: d2 -> sum over 6 bandwidths of exp(-d2/bw) ----
        // C/D layout: col = lane&15 (B row), row = (lane>>4)*4 + reg (A row)
        float lsum = 0.0f;
        const int rowA0 = ti * 256, colB0 = tj * 256;
        const int grb = rowA0 + wr * 128 + fgrp * 4;
        const int gcb = colB0 + wc * 64 + frow;
        float y2v[4];
#pragma unroll
        for (int ni = 0; ni < 4; ++ni) y2v[ni] = x2b[gcb + ni * 16];
#pragma unroll
        for (int mi = 0; mi < 8; ++mi) {
#pragma unroll
            for (int r = 0; r < 4; ++r) {
                const int gr = grb + mi * 16 + r;
                const float xa = x2a[gr];
#pragma unroll
                for (int ni = 0; ni < 4; ++ni) {
                    float d2 = fmaxf(xa + y2v[ni] - 2.0f * acc[mi][ni][r], 0.0f);
                    // t = exp(-d2/100); bw {100,50,20,10,5,1} -> t^{1,2,5,10,20,100}
                    float t1   = __expf(d2 * -0.01f);
                    float t2v  = t1 * t1;
                    float t4   = t2v * t2v;
                    float t5   = t4 * t1;
                    float t10  = t5 * t5;
                    float t20  = t10 * t10;
                    float t40  = t20 * t20;
                    float t80  = t40 * t40;
                    float t100 = t80 * t20;
                    float ksum = t1 + t2v + t5 + t10 + t20 + t100;
                    if (m != 1 && gr == gcb + ni * 16) ksum = 6.0f;  // exact diag
                    lsum += ksum;
                }
            }
        }

#pragma unroll
        for (int off = 32; off; off >>= 1) lsum += __shfl_down(lsum, off);
        __syncthreads();
        if (lane == 0) red[w] = lsum;
        __syncthreads();
        if (tid == 0) {
            float wgt = (m == 1) ? -2.0f : ((ti == tj) ? 1.0f : 2.0f);
            float tot = 0.0f;
#pragma unroll
            for (int i = 0; i < 8; ++i) tot += red[i];
            // loss = (S_ss - 2*S_st + S_tt) / (6 * 8192 * 8192)
            atomicAdd(out, tot * (wgt / 402653184.0f));
        }
        __syncthreads();
    }
}

extern "C" void kernel_launch(void* const* d_in, const int* in_sizes, int n_in,
                              void* d_out, int out_size, void* d_ws, size_t ws_size,
                              hipStream_t stream) {
    const float* src = (const float*)d_in[0];
    const float* tgt = (const float*)d_in[1];
    float* out = (float*)d_out;

    unsigned short* Sb = (unsigned short*)d_ws;
    unsigned short* Tb = Sb + (size_t)NROW * D_DIM;
    float* s2 = (float*)(Tb + (size_t)NROW * D_DIM);
    float* t2 = s2 + NROW;
    int* cnt = (int*)(t2 + NROW);

    mk_conv<<<NROW, 256, 0, stream>>>(src, Sb, s2, out, cnt, 1);
    mk_conv<<<NROW, 256, 0, stream>>>(tgt, Tb, t2, out, cnt, 0);
    mk_gemm<<<256, 512, 0, stream>>>(Sb, Tb, s2, t2, out, cnt);
}